// Round 5
// baseline (965.470 us; speedup 1.0000x reference)
//
#include <hip/hip_runtime.h>
#include <hip/hip_bf16.h>
#include <stdint.h>

#define NTOK 49
#define NH 8
#define NWIN 4096

typedef short bf16x8 __attribute__((ext_vector_type(8)));
typedef float f32x4 __attribute__((ext_vector_type(4)));

__device__ __forceinline__ f32x4 mfma16(bf16x8 a, bf16x8 b, f32x4 c) {
    return __builtin_amdgcn_mfma_f32_16x16x32_bf16(a, b, c, 0, 0, 0);
}
__device__ __forceinline__ bf16x8 ld8s(const unsigned short* p) {
    return *(const bf16x8*)p;
}
// packed fp32x2 -> bf16x2 (v_cvt_pk_bf16_f32 on gfx950)
__device__ __forceinline__ unsigned int pk2bf(float a, float b) {
    __hip_bfloat162 h = __float22bfloat162_rn(float2{a, b});
    return *reinterpret_cast<unsigned int*>(&h);
}
// store 4 floats as 4 consecutive bf16 (8B-aligned ds_write_b64)
__device__ __forceinline__ void st4bf(unsigned short* p, float a, float b, float c, float d) {
    uint2 u;
    u.x = pk2bf(a, b);
    u.y = pk2bf(c, d);
    *reinterpret_cast<uint2*>(p) = u;
}
__device__ __forceinline__ unsigned short f2bf(float f) {
    union { float f; unsigned int u; } v; v.f = f;
    unsigned int r = v.u + 0x7FFFu + ((v.u >> 16) & 1u);
    return (unsigned short)(r >> 16);
}

// ---------------------------------------------------------------------------
// K0: weights -> bf16; expand rel-pos bias to [8][64][64] fp32 with key
// padding mask baked in (-1e30 on key cols >= 49 -> exp() == 0).
// ---------------------------------------------------------------------------
__global__ void prep_kernel(const float* __restrict__ qkv_w,
                            const float* __restrict__ proj_w,
                            const float* __restrict__ bias_table,
                            const int* __restrict__ rel_idx,
                            unsigned short* __restrict__ wqkv,
                            unsigned short* __restrict__ wproj,
                            float* __restrict__ biasx)
{
    int i0 = blockIdx.x * blockDim.x + threadIdx.x;
    int stride = gridDim.x * blockDim.x;
    for (int t = i0; t < 768 * 256; t += stride) wqkv[t] = f2bf(qkv_w[t]);
    for (int t = i0; t < 256 * 256; t += stride) wproj[t] = f2bf(proj_w[t]);
    for (int t = i0; t < NH * 64 * 64; t += stride) {
        int h = t >> 12;
        int m = (t >> 6) & 63;   // query row
        int n = t & 63;          // key col
        float v;
        if (n >= NTOK)      v = -1e30f;
        else if (m >= NTOK) v = 0.0f;
        else                v = bias_table[rel_idx[m * NTOK + n] * NH + h];
        biasx[t] = v;
    }
}

// ---------------------------------------------------------------------------
// K1: fully fused per-window QKV + attention + proj. 256 thr = 4 waves.
//
// R4 structure, built for 3 blocks/CU (12 waves/CU = 3 waves/SIMD):
//   LDS = x_bf16 [64][264] (33792 B, padded rows zeroed)
//       + single 1-head staging buffer q[64][40]|k[64][40]|v^T[32][72]
//         (14848 B)                                    => 48640 B total.
//   No ao tile: wave = query-16-tile attention for ALL heads; each pass's
//   O^T fragment is shuffle-transposed in-register into a proj B-fragment
//   paf[head] (32 VGPRs, statically indexed -> pass loop fully unrolled).
//   Projection runs from registers, no LDS, no tail barrier.
//   Staging is single-buffered but all k/q/v ds_reads issue BEFORE the
//   barrier, so attention computes from registers while other waves
//   overwrite the buffer with the next head.
//   __launch_bounds__(256,3): both plausible arg2 semantics (blocks/CU,
//   waves/EU) coincide at 4-wave blocks -> combined reg cap ~170/wave.
//
// Layout conventions (mfma_f32_16x16x32_bf16):
//   A-frag: a[m = lane&15][k = (lane>>4)*8 + j]
//   B-frag: b[n = lane&15][k = (lane>>4)*8 + j]
//   C/D   : col(n) = lane&15, row(m) = (lane>>4)*4 + reg
// ---------------------------------------------------------------------------
__global__ __launch_bounds__(256, 3) void fused_kernel(
    const float* __restrict__ x,
    const float* __restrict__ qkv_b,
    const unsigned short* __restrict__ wqkv,
    const float* __restrict__ biasx,
    const unsigned short* __restrict__ wproj,
    const float* __restrict__ proj_b,
    float* __restrict__ out)
{
    __shared__ unsigned short smem[24320];   // 48640 B -> 3 blocks/CU
    unsigned short* xl = smem;               // [64][264] x bf16
    unsigned short* qs = smem + 16896;       // [64][40]  q*scale
    unsigned short* ks = qs + 2560;          // [64][40]  k
    unsigned short* vt = ks + 2560;          // [32][72]  v^T

    const int tid  = threadIdx.x;
    const int wv   = tid >> 6;           // 0..3
    const int lane = tid & 63;
    const int l16  = lane & 15;
    const int lq   = lane >> 4;
    const int w    = blockIdx.x;
    const float scale = 0.17677669529663687f;   // 32^-0.5

    const int wh = wv & 1;    // token half (QKV staging)
    const int jt = wv >> 1;   // QKV job triple (0..1)
    const int qt = wv;        // attention/proj: query 16-tile

    const float* xw = x + (size_t)w * (NTOK * 256);

    // ---- prologue: x -> LDS bf16, padded rows (49..63) zeroed ----
    for (int t = tid; t < 4096; t += 256) {
        int row = t >> 6;
        int col = (t & 63) << 2;
        float4 f;
        if (row < NTOK) f = *(const float4*)(xw + row * 256 + col);
        else { f.x = 0.f; f.y = 0.f; f.z = 0.f; f.w = 0.f; }
        st4bf(&xl[row * 264 + col], f.x, f.y, f.z, f.w);
    }
    __syncthreads();

    // ---- QKV stage for head h into the single staging buffer ----
    // 12 half-token jobs (6 ch-tiles x 2 token-halves), 3 per wave (even).
    auto stage = [&](int h) {
#pragma unroll
        for (int ti = 0; ti < 3; ++ti) {
            int tl   = jt * 3 + ti;            // 0..5
            int grp  = tl >> 1;                // 0=q 1=k 2=v
            int sub  = tl & 1;                 // 16-ch tile within head
            int tile = grp * 16 + 2 * h + sub; // of 48
            const unsigned short* bptr = wqkv + (size_t)(tile * 16 + l16) * 256 + lq * 8;
            bf16x8 bfr[8];
#pragma unroll
            for (int c = 0; c < 8; ++c) bfr[c] = ld8s(bptr + c * 32);

            f32x4 acc[2];
            { f32x4 z = {0.f,0.f,0.f,0.f}; acc[0] = z; acc[1] = z; }

#pragma unroll
            for (int c = 0; c < 8; ++c) {
                bf16x8 xb0 = ld8s(&xl[(wh * 32 + l16) * 264 + c * 32 + lq * 8]);
                bf16x8 xb1 = ld8s(&xl[(wh * 32 + 16 + l16) * 264 + c * 32 + lq * 8]);
                if (grp < 2) {   // swapped: D[ch][tok]
                    acc[0] = mfma16(bfr[c], xb0, acc[0]);
                    acc[1] = mfma16(bfr[c], xb1, acc[1]);
                } else {         // original: D[tok][ch] for v^T
                    acc[0] = mfma16(xb0, bfr[c], acc[0]);
                    acc[1] = mfma16(xb1, bfr[c], acc[1]);
                }
            }

            if (grp < 2) {
                int chb = tile * 16 + lq * 4;          // global channel base
                float4 bv = *(const float4*)(qkv_b + chb);
                int d0 = sub * 16 + lq * 4;            // channel within head
                unsigned short* dst = (grp == 0 ? qs : ks) + d0;
                float sc = (grp == 0) ? scale : 1.0f;
#pragma unroll
                for (int nt = 0; nt < 2; ++nt) {
                    int tok = wh * 32 + nt * 16 + l16;
                    st4bf(dst + tok * 40,
                          (acc[nt][0] + bv.x) * sc, (acc[nt][1] + bv.y) * sc,
                          (acc[nt][2] + bv.z) * sc, (acc[nt][3] + bv.w) * sc);
                }
            } else {
                int ch = tile * 16 + l16;
                float bv = qkv_b[ch];
                int d = sub * 16 + l16;                // d within head
                unsigned short* dst = vt + d * 72;
#pragma unroll
                for (int nt = 0; nt < 2; ++nt) {
                    int tok0 = wh * 32 + nt * 16 + lq * 4;
                    st4bf(dst + tok0, acc[nt][0] + bv, acc[nt][1] + bv,
                                      acc[nt][2] + bv, acc[nt][3] + bv);
                }
            }
        }
    };

    stage(0);
    __syncthreads();   // (A0) head-0 q/k/v visible

    const int q = qt * 16 + l16;
    const int srcA = l16 + ((2 * lq) & 3) * 16;
    const int srcB = srcA + 16;
    const int hi = lq >> 1;

    bf16x8 paf[NH];    // proj B-frags, one per head — statically indexed

#pragma unroll
    for (int p = 0; p < NH; ++p) {
        // ---- issue ALL staging reads, then release the buffer ----
        bf16x8 kf[4];
#pragma unroll
        for (int mt = 0; mt < 4; ++mt)
            kf[mt] = ld8s(&ks[(mt * 16 + l16) * 40 + lq * 8]);
        bf16x8 qf = ld8s(&qs[(qt * 16 + l16) * 40 + lq * 8]);
        bf16x8 vf[2][2];
#pragma unroll
        for (int kc = 0; kc < 2; ++kc)
#pragma unroll
            for (int mt = 0; mt < 2; ++mt)
                vf[mt][kc] = ld8s(&vt[(mt * 16 + l16) * 72 + kc * 32 + lq * 8]);
        __syncthreads();   // (B) reads complete -> buffer free for next head

        // ================= Sᵀ = K·Qᵀ (head p) =================
        f32x4 se[4];
#pragma unroll
        for (int mt = 0; mt < 4; ++mt) { f32x4 z = {0.f,0.f,0.f,0.f}; se[mt] = z; }
#pragma unroll
        for (int mt = 0; mt < 4; ++mt)
            se[mt] = mfma16(kf[mt], qf, se[mt]);
        // lane holds: query = qt*16 + l16, key = mt*16 + lq*4 + r

        // bias + exp + in-lane sum (no max-subtract: |s| bounded ~15)
        const float* bh = biasx + (p << 12);
        float lsum = 0.0f;
#pragma unroll
        for (int mt = 0; mt < 4; ++mt) {
            float4 bb = *(const float4*)(bh + q * 64 + mt * 16 + lq * 4);
            float e0 = __expf(se[mt][0] + bb.x);
            float e1 = __expf(se[mt][1] + bb.y);
            float e2 = __expf(se[mt][2] + bb.z);
            float e3 = __expf(se[mt][3] + bb.w);
            se[mt][0] = e0; se[mt][1] = e1;
            se[mt][2] = e2; se[mt][3] = e3;
            lsum += (e0 + e1) + (e2 + e3);
        }
        lsum += __shfl_xor(lsum, 16);
        lsum += __shfl_xor(lsum, 32);
        float rv = 1.0f / lsum;

        // pack normalized P: P0[mt] = keys (lq*4+0,1), P1[mt] = keys (lq*4+2,3)
        unsigned int P0[4], P1[4];
#pragma unroll
        for (int mt = 0; mt < 4; ++mt) {
            P0[mt] = pk2bf(se[mt][0] * rv, se[mt][1] * rv);
            P1[mt] = pk2bf(se[mt][2] * rv, se[mt][3] * rv);
        }
        // redistribute to PV B-frag in-register (16-lane-group transpose)
        bf16x8 pf[2];
#pragma unroll
        for (int kc = 0; kc < 2; ++kc) {
            unsigned int a0 = (unsigned int)__shfl((int)P0[2 * kc],     srcA);
            unsigned int a1 = (unsigned int)__shfl((int)P0[2 * kc + 1], srcA);
            unsigned int b0 = (unsigned int)__shfl((int)P1[2 * kc],     srcA);
            unsigned int b1 = (unsigned int)__shfl((int)P1[2 * kc + 1], srcA);
            unsigned int c0 = (unsigned int)__shfl((int)P0[2 * kc],     srcB);
            unsigned int c1 = (unsigned int)__shfl((int)P0[2 * kc + 1], srcB);
            unsigned int d0 = (unsigned int)__shfl((int)P1[2 * kc],     srcB);
            unsigned int d1 = (unsigned int)__shfl((int)P1[2 * kc + 1], srcB);
            union { bf16x8 v; unsigned int u[4]; } t;
            t.u[0] = hi ? a1 : a0;
            t.u[1] = hi ? b1 : b0;
            t.u[2] = hi ? c1 : c0;
            t.u[3] = hi ? d1 : d0;
            pf[kc] = t.v;
        }

        // ================= Oᵀ = Vᵀ·P =================
        f32x4 ot[2];
        { f32x4 z = {0.f,0.f,0.f,0.f}; ot[0] = z; ot[1] = z; }
#pragma unroll
        for (int kc = 0; kc < 2; ++kc)
#pragma unroll
            for (int mt = 0; mt < 2; ++mt)
                ot[mt] = mfma16(vf[mt][kc], pf[kc], ot[mt]);
        // lane holds: d = mt*16 + lq*4 + r, query = qt*16 + l16

        // ---- Oᵀ -> proj B-frag in-register (same transpose pattern) ----
        {
            unsigned int Q0[2], Q1[2];
#pragma unroll
            for (int mt = 0; mt < 2; ++mt) {
                Q0[mt] = pk2bf(ot[mt][0], ot[mt][1]);
                Q1[mt] = pk2bf(ot[mt][2], ot[mt][3]);
            }
            unsigned int a0 = (unsigned int)__shfl((int)Q0[0], srcA);
            unsigned int a1 = (unsigned int)__shfl((int)Q0[1], srcA);
            unsigned int b0 = (unsigned int)__shfl((int)Q1[0], srcA);
            unsigned int b1 = (unsigned int)__shfl((int)Q1[1], srcA);
            unsigned int c0 = (unsigned int)__shfl((int)Q0[0], srcB);
            unsigned int c1 = (unsigned int)__shfl((int)Q0[1], srcB);
            unsigned int d0 = (unsigned int)__shfl((int)Q1[0], srcB);
            unsigned int d1 = (unsigned int)__shfl((int)Q1[1], srcB);
            union { bf16x8 v; unsigned int u[4]; } t;
            t.u[0] = hi ? a1 : a0;   // d = lq*8 + {0,1}
            t.u[1] = hi ? b1 : b0;   // d = lq*8 + {2,3}
            t.u[2] = hi ? c1 : c0;   // d = lq*8 + {4,5}
            t.u[3] = hi ? d1 : d0;   // d = lq*8 + {6,7}
            paf[p] = t.v;            // b[tok = l16][k = lq*8 + j] for head p
        }

        // ---- overlap: stage next head while this head's math retires ----
        if (p < NH - 1) {
            stage(p + 1);
            __syncthreads();   // (A) next head's q/k/v visible
        }
    }

    // ================= projection from register paf =================
    const int tok = qt * 16 + l16;
#pragma unroll
    for (int t4 = 0; t4 < 16; ++t4) {
        const unsigned short* wp = wproj + (size_t)(t4 * 16 + l16) * 256 + lq * 8;
        f32x4 acc = {0.f, 0.f, 0.f, 0.f};
#pragma unroll
        for (int c = 0; c < 8; ++c) {
            bf16x8 wfr = ld8s(wp + c * 32);
            acc = mfma16(wfr, paf[c], acc);   // k-chunk c == head c (32 ch)
        }
        int chb = t4 * 16 + lq * 4;
        float4 pb = *(const float4*)(proj_b + chb);
        if (tok < NTOK) {
            float4 o;
            o.x = acc[0] + pb.x;
            o.y = acc[1] + pb.y;
            o.z = acc[2] + pb.z;
            o.w = acc[3] + pb.w;
            *(float4*)(out + ((size_t)w * NTOK + tok) * 256 + chb) = o;
        }
    }
}

// ---------------------------------------------------------------------------
extern "C" void kernel_launch(void* const* d_in, const int* in_sizes, int n_in,
                              void* d_out, int out_size, void* d_ws, size_t ws_size,
                              hipStream_t stream) {
    const float* x          = (const float*)d_in[0];
    const float* qkv_w      = (const float*)d_in[1];
    const float* qkv_b      = (const float*)d_in[2];
    const float* proj_w     = (const float*)d_in[3];
    const float* proj_b     = (const float*)d_in[4];
    const float* bias_table = (const float*)d_in[5];
    const int*   rel_idx    = (const int*)d_in[6];
    float* out = (float*)d_out;

    char* ws = (char*)d_ws;
    unsigned short* wqkv  = (unsigned short*)ws;                 // 393216 B
    unsigned short* wproj = (unsigned short*)(ws + 393216);      // 131072 B
    float*          biasx = (float*)(ws + 524288);               // 131072 B

    prep_kernel<<<256, 256, 0, stream>>>(qkv_w, proj_w, bias_table, rel_idx,
                                         wqkv, wproj, biasx);
    fused_kernel<<<NWIN, 256, 0, stream>>>(x, qkv_b, wqkv, biasx, wproj,
                                           proj_b, out);
}